// Round 7
// baseline (512.035 us; speedup 1.0000x reference)
//
#include <hip/hip_runtime.h>

// HyperConnections fused kernel, v7.
// out[(b*S+s)*T+t, d] = res[...] + c[s] * rmsnorm(sum_s h_pre[s]*res[...])[d]
// where c[s] = sum_r Sinkhorn(exp(H_res))[s][r] * 2*sigmoid(H_post[r]).
//
// v7 changes vs v6 (454.4 us; v5 451.5; all versions within 1% despite wildly
// different execution structure -> execution-side limits ruled out):
//  - Wave = stream. The one invariant of v1..v6 was each wave interleaving
//    8 regions 16.78 MiB apart (4 stream reads + 4 stream writes). The
//    proven 6.3-6.5 TB/s streams on this chip (fills, float4 copy) walk ONE
//    contiguous region per wave. Now: 4-wave block owns 4 consecutive
//    t-rows; wave s reads a contiguous 16 KiB of stream s and writes the
//    same 16 KiB region of out. Cross-stream aggregate via LDS agg[4][1024]
//    with a rotated row schedule (bijective per step, barrier between
//    steps). 5 barriers / 64 KiB -- v5 proved barriers at this density are
//    free. LDS 16 KiB/block.
//  - Coefficients stay hoisted in the 1-block precompute kernel.

#define S_ 4
#define T_ 4096
#define D_ 1024
#define NITER_ 20
#define EPSF_ 1e-5f

typedef float f32x4 __attribute__((ext_vector_type(4)));

__device__ float g_coef[8];   // [0..3] = h_pre[s], [4..7] = c[s]

__global__ void hyperconn_coeff(const float* __restrict__ hpre_l,
                                const float* __restrict__ hpost_l,
                                const float* __restrict__ hres)
{
    if (threadIdx.x != 0) return;

    float M[S_][S_];
    #pragma unroll
    for (int i = 0; i < S_; ++i)
        #pragma unroll
        for (int j = 0; j < S_; ++j)
            M[i][j] = __expf(hres[i * S_ + j]);

    for (int it = 0; it < NITER_; ++it) {
        #pragma unroll
        for (int i = 0; i < S_; ++i) {
            float inv = 1.0f / (M[i][0] + M[i][1] + M[i][2] + M[i][3] + EPSF_);
            M[i][0] *= inv; M[i][1] *= inv; M[i][2] *= inv; M[i][3] *= inv;
        }
        #pragma unroll
        for (int j = 0; j < S_; ++j) {
            float inv = 1.0f / (M[0][j] + M[1][j] + M[2][j] + M[3][j] + EPSF_);
            M[0][j] *= inv; M[1][j] *= inv; M[2][j] *= inv; M[3][j] *= inv;
        }
    }

    #pragma unroll
    for (int s = 0; s < S_; ++s) {
        g_coef[s] = 1.0f / (1.0f + __expf(-hpre_l[s]));    // h_pre[s]
        float c = 0.0f;
        #pragma unroll
        for (int r = 0; r < S_; ++r)
            c += M[s][r] * (2.0f / (1.0f + __expf(-hpost_l[r])));
        g_coef[S_ + s] = c;                                 // c[s]
    }
}

__global__ __launch_bounds__(256, 4) void hyperconn_main(
    const float* __restrict__ res,
    const float* __restrict__ w,
    float* __restrict__ out)
{
    const int lane = threadIdx.x & 63;
    const int wv   = threadIdx.x >> 6;          // wave index == stream index
    const int n    = blockIdx.x;                // (B*T)/4 blocks
    const int b    = n >> 10;                   // T/4 = 1024 blocks per batch
    const int t0   = (n & 1023) << 2;           // 4 consecutive t-rows

    __shared__ __align__(16) float s_agg[4][D_];   // 16 KiB: agg rows
    __shared__ float s_inv[4];                     // inv_rms per row

    // ---- per-wave coefficients (uniform within wave) ----
    const float h = g_coef[wv];                 // h_pre[stream wv]
    const float c = g_coef[4 + wv];             // c[stream wv]

    const f32x4* res4 = reinterpret_cast<const f32x4*>(res);
    const f32x4* w4   = reinterpret_cast<const f32x4*>(w);
    f32x4*       out4 = reinterpret_cast<f32x4*>(out);

    const int    D4   = D_ / 4;                 // 256 f32x4 per row
    // wave wv's contiguous 16 KiB segment: stream wv, rows t0..t0+3
    const size_t base = ((size_t)(b * S_ + wv) * T_ + t0) * D4;

    // ---- weight fragment (reused across all 4 rows) ----
    f32x4 wt[4];
    #pragma unroll
    for (int k = 0; k < 4; ++k)
        wt[k] = w4[(k << 6) + lane];

    // ---- contiguous 16 KiB read: 4 rows x 4 chunks ----
    f32x4 r[4][4];
    #pragma unroll
    for (int j = 0; j < 4; ++j)
        #pragma unroll
        for (int k = 0; k < 4; ++k)
            r[j][k] = res4[base + j * D4 + (k << 6) + lane];

    // ---- accumulate h*r into LDS agg with rotated row schedule ----
    // step 0: wave wv initializes row wv; steps 1..3: adds to row (wv+st)&3.
    // Each step's wave->row map is a bijection -> no write races.
    {
        f32x4* dst = reinterpret_cast<f32x4*>(&s_agg[wv][0]);
        #pragma unroll
        for (int k = 0; k < 4; ++k)
            dst[(k << 6) + lane] = h * r[wv][k];
    }
    __syncthreads();
    #pragma unroll
    for (int st = 1; st < 4; ++st) {
        const int j = (wv + st) & 3;
        f32x4* dst = reinterpret_cast<f32x4*>(&s_agg[j][0]);
        #pragma unroll
        for (int k = 0; k < 4; ++k)
            dst[(k << 6) + lane] += h * r[j][k];
        __syncthreads();
    }

    // ---- wave wv reduces row wv: ssq + butterfly -> inv_rms ----
    {
        const f32x4* src = reinterpret_cast<const f32x4*>(&s_agg[wv][0]);
        float ssq = 0.0f;
        #pragma unroll
        for (int k = 0; k < 4; ++k) {
            const f32x4 a = src[(k << 6) + lane];
            ssq += a.x*a.x + a.y*a.y + a.z*a.z + a.w*a.w;
        }
        #pragma unroll
        for (int off = 1; off <= 32; off <<= 1)
            ssq += __shfl_xor(ssq, off, 64);
        if (lane == 0)
            s_inv[wv] = rsqrtf(ssq * (1.0f / (float)D_) + EPSF_);
    }
    __syncthreads();

    // ---- contiguous 16 KiB write: out stream wv, rows t0..t0+3 ----
    #pragma unroll
    for (int j = 0; j < 4; ++j) {
        const float inv = s_inv[j];
        const f32x4* aj = reinterpret_cast<const f32x4*>(&s_agg[j][0]);
        #pragma unroll
        for (int k = 0; k < 4; ++k) {
            const f32x4 nrm = aj[(k << 6) + lane] * inv * wt[k];
            out4[base + j * D4 + (k << 6) + lane] = r[j][k] + nrm * c;
        }
    }
}

extern "C" void kernel_launch(void* const* d_in, const int* in_sizes, int n_in,
                              void* d_out, int out_size, void* d_ws, size_t ws_size,
                              hipStream_t stream) {
    const float* res     = (const float*)d_in[0];   // (B*S, T, D) f32
    const float* weight  = (const float*)d_in[1];   // (D,) f32
    const float* hpre_l  = (const float*)d_in[2];   // (S,) f32
    const float* hpost_l = (const float*)d_in[3];   // (S,) f32
    const float* hres    = (const float*)d_in[4];   // (S,S) f32
    float*       out     = (float*)d_out;

    hyperconn_coeff<<<1, 64, 0, stream>>>(hpre_l, hpost_l, hres);

    // one block per 4 consecutive t-rows
    const int n_rows = in_sizes[0] / (S_ * D_);     // 16384 for B=4,T=4096
    hyperconn_main<<<n_rows >> 2, 256, 0, stream>>>(res, weight, out);
}